// Round 8
// baseline (380.817 us; speedup 1.0000x reference)
//
#include <hip/hip_runtime.h>

// Problem constants (B,N,HD,NH,KVH fixed by reference)
#define BB   2
#define NN   2048
#define HDIM 2048
#define NHD  16
#define KVHD 4
#define DD   128
#define KVW  1024          // kv buffer width: k[0:512] | v[512:1024]
#define MTOK (BB*NN)       // 4096 token rows
#define NSPLIT 7           // q-tiles 0..6 are j-split into 2 pieces (linear O/l combine)

typedef _Float16 h8 __attribute__((ext_vector_type(8)));
typedef _Float16 h4 __attribute__((ext_vector_type(4)));
typedef float    f4 __attribute__((ext_vector_type(4)));
typedef float    fx16 __attribute__((ext_vector_type(16)));
typedef short    b8 __attribute__((ext_vector_type(8)));   // 8 bf16
typedef unsigned int u4v __attribute__((ext_vector_type(4)));

static __device__ __forceinline__ fx16 mfma32h(h8 a, h8 b, fx16 c) {
    return __builtin_amdgcn_mfma_f32_32x32x16_f16(a, b, c, 0, 0, 0);
}
static __device__ __forceinline__ f4 mfma16(h8 a, h8 b, f4 c) {
    return __builtin_amdgcn_mfma_f32_16x16x32_f16(a, b, c, 0, 0, 0);
}
static __device__ __forceinline__ fx16 mfma32b(b8 a, b8 b, fx16 c) {
    return __builtin_amdgcn_mfma_f32_32x32x16_bf16(a, b, c, 0, 0, 0);
}

// float -> bf16 RTNE (verified byte-exact in the passing kernels).
// NOTE: do NOT substitute v_cvt_pk_bf16_f32 inline asm -- its half-packing
// order on gfx950 differs from the naive assumption (rounds 0/2 failed on it).
static __device__ __forceinline__ unsigned short f2bf(float f) {
    unsigned int u = __float_as_uint(f);
    u += 0x7FFF + ((u >> 16) & 1);
    return (unsigned short)(u >> 16);
}

// async global->LDS, 16B per lane. LDS dst must be wave-uniform base + lane*16.
// Global source address is per-lane (gather) -> we may permute sources freely.
static __device__ __forceinline__ void gload_lds16(const void* g, void* l) {
    __builtin_amdgcn_global_load_lds(
        (const __attribute__((address_space(1))) void*)g,
        (__attribute__((address_space(3))) void*)l, 16, 0, 0);
}

// ---------------- RMSNorm (fp32 in, f16 out) ----------------
__global__ __launch_bounds__(256) void rmsnorm_k(const float* __restrict__ t,
                                                 const float* __restrict__ wn,
                                                 _Float16* __restrict__ xh) {
    const int row = blockIdx.x, tid = threadIdx.x;
    const float* rp = t + (size_t)row * HDIM;
    float4 v[2];
    float ss = 0.f;
    #pragma unroll
    for (int p = 0; p < 2; ++p) {
        float4 x = *(const float4*)(rp + (p * 256 + tid) * 4);
        v[p] = x;
        ss += x.x * x.x + x.y * x.y + x.z * x.z + x.w * x.w;
    }
    #pragma unroll
    for (int off = 32; off; off >>= 1) ss += __shfl_xor(ss, off, 64);
    __shared__ float sred[4];
    if ((tid & 63) == 0) sred[tid >> 6] = ss;
    __syncthreads();
    float rs = rsqrtf((sred[0] + sred[1] + sred[2] + sred[3]) * (1.0f / HDIM)
                      + 1.1920928955078125e-07f);
    _Float16* op = xh + (size_t)row * HDIM;
    #pragma unroll
    for (int p = 0; p < 2; ++p) {
        int base = (p * 256 + tid) * 4;
        float4 w = *(const float4*)(wn + base);
        h4 o;
        o[0] = (_Float16)(v[p].x * rs * w.x);
        o[1] = (_Float16)(v[p].y * rs * w.y);
        o[2] = (_Float16)(v[p].z * rs * w.z);
        o[3] = (_Float16)(v[p].w * rs * w.w);
        *(h4*)(op + base) = o;
    }
}

// ---------------- fused fp32 -> f16 convert of all 4 weight matrices ---------
__global__ __launch_bounds__(256) void cvtall_k(const float* __restrict__ Wq,
                                                const float* __restrict__ Wk,
                                                const float* __restrict__ Wv,
                                                const float* __restrict__ Wo,
                                                _Float16* __restrict__ wq_h,
                                                _Float16* __restrict__ wkv_h,
                                                _Float16* __restrict__ wo_h) {
    int blk = blockIdx.x;
    const float* src; _Float16* dst; int off;
    if (blk < 4096)      { src = Wq; dst = wq_h;               off = blk; }
    else if (blk < 5120) { src = Wk; dst = wkv_h;              off = blk - 4096; }
    else if (blk < 6144) { src = Wv; dst = wkv_h + 512 * HDIM; off = blk - 5120; }
    else                 { src = Wo; dst = wo_h;               off = blk - 6144; }
    int i = off * 1024 + threadIdx.x * 4;
    float4 v = *(const float4*)(src + i);
    h4 o; o[0] = (_Float16)v.x; o[1] = (_Float16)v.y;
    o[2] = (_Float16)v.z; o[3] = (_Float16)v.w;
    *(h4*)(dst + i) = o;
}

// bias concat [bq | bk | bv] (3072) + zero the vsum accumulator (1024 floats)
__global__ void biascat_k(const float* __restrict__ bq, const float* __restrict__ bk,
                          const float* __restrict__ bv,
                          float* __restrict__ bqkv, float* __restrict__ vsum) {
    int i = blockIdx.x * 256 + threadIdx.x;   // 3072 total
    bqkv[i] = (i < 2048) ? bq[i] : (i < 2560) ? bk[i - 2048] : bv[i - 2560];
    if (i < 1024) vsum[i] = 0.f;
}

// ---------------- V transpose + f16->bf16: kv V-part -> vt[b][kvh][d][pi(N)] ---
// Token column index has bits 2<->3 swapped (involution). PV's 32x32 A-frag
// k-slot s then aligns with the lane-local rows of the 32x32 QK^T output:
// pa[ks] element e = P(reg 8*ks+e) -- P never leaves registers in attn_k.
__global__ __launch_bounds__(256) void vtrans_k(const _Float16* __restrict__ kv,
                                                unsigned short* __restrict__ vt) {
    const int tid = threadIdx.x;
    const int tok = blockIdx.x * 64 + (tid & 63);
    const int kvh = blockIdx.y;
    const int d0 = (tid >> 6) * 32;
    const int b = tok >> 11, n = tok & (NN - 1);
    const int n2 = (n & ~12) | ((n & 4) << 1) | ((n & 8) >> 1);  // swap bits 2,3
    const _Float16* src = kv + (size_t)tok * KVW + 512 + kvh * DD + d0;
    unsigned short* dstb = vt + ((size_t)(b * KVHD + kvh) * DD) * NN + n2;
    #pragma unroll
    for (int u = 0; u < 4; ++u) {
        h8 v = *(const h8*)(src + u * 8);
        #pragma unroll
        for (int e = 0; e < 8; ++e)
            dstb[(size_t)(d0 + u * 8 + e) * NN] = f2bf((float)v[e]);
    }
}

// ---------------- GEMM  C[M,Nout] = A[M,K] * Bw[Nout,K]^T + bias ----------------
// 128x128 tile, 256 thr (4 waves, 2x2), BK=64, global_load_lds x16,
// XOR-swizzled LDS chunks (conflict-free b128 reads).
// MODE 1: f32 out; MODE 2: split out (col<2048 -> Cout f16 w2048,
// else -> Cout2 f16 w1024). Split boundary is 128-tile-aligned => block-uniform.
template <int MODE>
__global__ __launch_bounds__(256, 2) void gemm_bt(const _Float16* __restrict__ A,
                                                  const _Float16* __restrict__ Bw,
                                                  const float* __restrict__ bias,
                                                  void* __restrict__ Cout,
                                                  void* __restrict__ Cout2,
                                                  int Ndim, int K) {
    __shared__ _Float16 sA[128 * 64];
    __shared__ _Float16 sB[128 * 64];
    const int tid = threadIdx.x;
    const int lane = tid & 63, w = tid >> 6;
    const int ln = lane & 15, quad = lane >> 4;
    const int wm = w >> 1, wn = w & 1;
    const int m0 = blockIdx.y * 128, n0 = blockIdx.x * 128;

    f4 acc[4][4] = {};
    for (int k0 = 0; k0 < K; k0 += 64) {
        #pragma unroll
        for (int it = 0; it < 4; ++it) {
            int chunk = it * 256 + tid;            // 1024 chunks of 8 halves
            int row = chunk >> 3, p = chunk & 7;
            int c = p ^ (row & 7);                 // logical source chunk
            gload_lds16(A + (size_t)(m0 + row) * K + k0 + c * 8, sA + chunk * 8);
            gload_lds16(Bw + (size_t)(n0 + row) * K + k0 + c * 8, sB + chunk * 8);
        }
        __syncthreads();
        #pragma unroll
        for (int kk = 0; kk < 2; ++kk) {
            h8 af[4], bf[4];
            #pragma unroll
            for (int mt = 0; mt < 4; ++mt)
                af[mt] = *(const h8*)&sA[(wm * 64 + mt * 16 + ln) * 64 +
                                         (((kk * 4 + quad) ^ (ln & 7)) << 3)];
            #pragma unroll
            for (int nt = 0; nt < 4; ++nt)
                bf[nt] = *(const h8*)&sB[(wn * 64 + nt * 16 + ln) * 64 +
                                         (((kk * 4 + quad) ^ (ln & 7)) << 3)];
            #pragma unroll
            for (int mt = 0; mt < 4; ++mt)
                #pragma unroll
                for (int nt = 0; nt < 4; ++nt)
                    acc[mt][nt] = mfma16(af[mt], bf[nt], acc[mt][nt]);
        }
        __syncthreads();
    }
    #pragma unroll
    for (int mt = 0; mt < 4; ++mt) {
        int rowb = m0 + wm * 64 + mt * 16 + quad * 4;   // C: row = quad*4+reg
        #pragma unroll
        for (int nt = 0; nt < 4; ++nt) {
            int col = n0 + wn * 64 + nt * 16 + ln;      // C: col = lane&15
            float bv = bias[col];
            #pragma unroll
            for (int r = 0; r < 4; ++r) {
                float v = acc[mt][nt][r] + bv;
                if (MODE == 1)
                    ((float*)Cout)[(size_t)(rowb + r) * Ndim + col] = v;
                else {  // MODE 2: split q|kv
                    if (n0 < 2048)
                        ((_Float16*)Cout)[(size_t)(rowb + r) * HDIM + col] = (_Float16)v;
                    else
                        ((_Float16*)Cout2)[(size_t)(rowb + r) * KVW + (col - 2048)] = (_Float16)v;
                }
            }
        }
    }
}

// ---------------- attn piece table, GLOBALLY sorted by length (LPT) ----------
// code = x | (p<<8) | (split<<16). Lengths (in 32-j iters) desc:
// 36,32,32,32,30,30,28,28,28,26,26,24,24,24,22,22,20,20,20,16,12,8,4
__device__ __constant__ int piece_tab[23] = {
    7,                      // c0  whole x=7   len 36
    0x10000, 0x10100,       // c1,2 split x=0  len 32
    8,                      // c3  whole x=8   len 32
    0x10001, 0x10101,       // c4,5 split x=1  len 30
    0x10002, 0x10102,       // c6,7 split x=2  len 28
    9,                      // c8  whole x=9   len 28
    0x10003, 0x10103,       // c9,10 split x=3 len 26
    0x10004, 0x10104,       // c11,12 split x=4 len 24
    10,                     // c13 whole x=10  len 24
    0x10005, 0x10105,       // c14,15 split x=5 len 22
    0x10006, 0x10106,       // c16,17 split x=6 len 20
    11, 12, 13, 14, 15      // c18..22 whole   len 20,16,12,8,4
};

// ---------------- Flash attention, inverted-causal (attend j > i) ----------------
// No-max softmax (scores bounded => P=exp(s) exact in fp32/bf16 range) => O and l
// are LINEAR in the j-range: split pieces sum with no rescaling (combine_k).
// QK^T via 32x32x16 f16 MFMA, swapped operands (A=K, B=Q -> D[m=j][n=q=l5]);
// V columns bit-2<->3-swapped (vtrans_k) => P packed in register order, no LDS.
// BN=32 j-tiles: LDS 32KB/block -> 4-5 blocks/CU (16-20 waves, was 2 blocks /
// 8 waves) to cover the dependency stalls that capped round 6 at 54% pipe-busy.
// XOR swizzles carry row-high-bit terms (^(row>>3)&3 for K 16-chunk rows,
// ^(row>>2)&3 for V 4-chunk rows): lanes 8/16/24 apart previously aliased to
// the same bank set (row strides are 0 mod 128B) -> 4-way conflicts; now only
// the free 2-way remains. Same involution on stage source and read.
// LPT 1-D dispatch (class = blockIdx.x>>5 desc length, hb = blockIdx.x&31).
__global__ __launch_bounds__(256, 4) void attn_k(const _Float16* __restrict__ qh,
                                                 const _Float16* __restrict__ kvp,
                                                 const unsigned short* __restrict__ vt,
                                                 _Float16* __restrict__ ah,
                                                 float* __restrict__ O_ws,
                                                 float* __restrict__ l_ws) {
    __shared__ _Float16 s_k[2][32 * 128];        // K tiles [j][d] f16, 16KB
    __shared__ unsigned short s_v[2][128 * 32];  // V^T tiles [d][j'] bf16, 16KB
    const int tid = threadIdx.x;
    const int lane = tid & 63, w = tid >> 6;     // 4 waves
    const int l5 = lane & 31, hi = lane >> 5;
    const int idx = blockIdx.x;                  // 736 = 23 classes x 32 (h,b)
    const int hb = idx & 31;
    const int h = hb & 15, b = hb >> 4;
    const int code = piece_tab[idx >> 5];
    const int x = code & 255, p = (code >> 8) & 1;
    const bool is_split = (code >> 16) & 1;
    int jlo, jhi;
    if (is_split) { int len = 32 - 2 * x; jlo = 4 * x + p * len; jhi = jlo + len; }
    else          { jlo = 4 * x; jhi = 64; }
    const int i0 = x * 128;
    const int kvh = h & 3;                       // head h uses kv head h % KVH
    const int qg = i0 + w * 32 + l5;             // this lane's q row (in batch)

    // Q fragments: B[n=q=l5][k=hi*8+e]; chunk kc covers d = kc*16 + hi*8 + e
    h8 qf[8];
    {
        const _Float16* qrow =
            qh + ((size_t)(b * NN + qg)) * HDIM + h * DD;
        #pragma unroll
        for (int kc = 0; kc < 8; ++kc)
            qf[kc] = *(const h8*)(qrow + kc * 16 + hi * 8);
    }

    b8 ones;
    #pragma unroll
    for (int e = 0; e < 8; ++e) ones[e] = (short)0x3F80;   // bf16 1.0

    fx16 O[4] = {};   // D[m=q(32)][n=d 32-block], 4 d-blocks
    fx16 OS = {};     // l via ones-column (all cols equal)

    // stage 32-wide j-tile jt into buffer bufi (256 thr, 2+2 chunk iters)
    auto stage = [&](int jt, int bufi) {
        const int j0s = jt * 32;
        #pragma unroll
        for (int itr = 0; itr < 2; ++itr) {      // K: 32 rows x 16 chunks
            int chunk = itr * 256 + tid;
            int jj = chunk >> 4, pp = chunk & 15;
            int c = pp ^ (jj & 15) ^ ((jj >> 3) & 3);
            gload_lds16(kvp + ((size_t)(b * NN + j0s + jj)) * KVW + kvh * DD + c * 8,
                        &s_k[bufi][chunk * 8]);
        }
        #pragma unroll
        for (int itr = 0; itr < 2; ++itr) {      // V^T: 128 rows x 4 chunks
            int chunk = itr * 256 + tid;
            int d = chunk >> 2, pp = chunk & 3;
            int c = pp ^ (d & 3) ^ ((d >> 2) & 3);
            gload_lds16(vt + ((size_t)(b * KVHD + kvh) * DD + d) * NN + j0s + c * 8,
                        &s_v[bufi][chunk * 8]);
        }
    };

    stage(jlo, 0);
    for (int jt = jlo; jt < jhi; ++jt) {
        const int j0 = jt * 32;
        const int cur = (jt - jlo) & 1;
        __syncthreads();                           // buf[cur] ready
        if (jt + 1 < jhi) stage(jt + 1, cur ^ 1);  // prefetch during compute

        // S^T = K Q^T : one 32-j block; A=K-frag (row l5), B=qf
        fx16 sc = {};
        #pragma unroll
        for (int kc = 0; kc < 8; ++kc) {
            int cs = ((kc * 2 + hi) ^ (l5 & 15) ^ ((l5 >> 3) & 3)) << 3;
            h8 kf = *(const h8*)&s_k[cur][l5 * 128 + cs];
            sc = mfma32h(kf, qf[kc], sc);
        }

        const bool need_mask = (jt < 4 * x + 4);   // masked iters are in piece 0
        // mask + exp + bf16 pack (verified byte order), in register order
        unsigned int pwod[8];
        #pragma unroll
        for (int pr = 0; pr < 8; ++pr) {
            float s0 = sc[2 * pr], s1 = sc[2 * pr + 1];
            if (need_mask) {
                int rg0 = 2 * pr;              // even: rg0&3 in {0,2} -> jg1=jg0+1
                int jg0 = j0 + (rg0 & 3) + 8 * (rg0 >> 2) + 4 * hi;
                if (jg0 <= qg) s0 = -1e9f;     // faithful inverted mask
                if (jg0 + 1 <= qg) s1 = -1e9f;
            }
            pwod[pr] = (unsigned int)f2bf(__expf(s0)) |
                       ((unsigned int)f2bf(__expf(s1)) << 16);
        }
        u4v w0v = {pwod[0], pwod[1], pwod[2], pwod[3]};
        u4v w1v = {pwod[4], pwod[5], pwod[6], pwod[7]};
        b8 pa0 = __builtin_bit_cast(b8, w0v);  // k-slots 0..15  (regs 0..7)
        b8 pa1 = __builtin_bit_cast(b8, w1v);  // k-slots 16..31 (regs 8..15)

        // O += P V ; OS += P 1   (A[m=q=l5][k], B[n=d][k=j'])
        #pragma unroll
        for (int ks = 0; ks < 2; ++ks) {
            b8 pa = ks ? pa1 : pa0;
            #pragma unroll
            for (int dblk = 0; dblk < 4; ++dblk) {
                b8 bv = *(const b8*)&s_v[cur][(dblk * 32 + l5) * 32 +
                         (((ks * 2 + hi) ^ (l5 & 3) ^ ((l5 >> 2) & 3)) << 3)];
                O[dblk] = mfma32b(pa, bv, O[dblk]);
            }
            OS = mfma32b(pa, ones, OS);
        }
    }

    // epilogue. 32x32 C-layout: col=l5=d-local, row=(rg&3)+8*(rg>>2)+4*hi=q-local.
    if (is_split) {
        // write f32 partials (no divide) for combine_k
        size_t po = (((size_t)(b * NHD + h) * NSPLIT + x) * 2 + p);
        float* Op = O_ws + po * 16384;
        float* Lp = l_ws + po * 128;
        #pragma unroll
        for (int nt4 = 0; nt4 < 4; ++nt4)
            #pragma unroll
            for (int rg = 0; rg < 16; ++rg) {
                int q = (rg & 3) + 8 * (rg >> 2) + 4 * hi;
                Op[(w * 32 + q) * 128 + nt4 * 32 + l5] = O[nt4][rg];
            }
        if (l5 == 0) {
            #pragma unroll
            for (int rg = 0; rg < 16; ++rg) {
                int q = (rg & 3) + 8 * (rg >> 2) + 4 * hi;
                Lp[w * 32 + q] = OS[rg];
            }
        }
    } else {
        // Row N-1: l=0 -> NaN, overwritten by fixup kernels.
        float inv_l[16];
        #pragma unroll
        for (int rg = 0; rg < 16; ++rg) inv_l[rg] = 1.0f / OS[rg];
        #pragma unroll
        for (int nt4 = 0; nt4 < 4; ++nt4)
            #pragma unroll
            for (int rg = 0; rg < 16; ++rg) {
                int q = (rg & 3) + 8 * (rg >> 2) + 4 * hi;
                ah[((size_t)(b * NN + i0 + w * 32 + q)) * HDIM + h * DD + nt4 * 32 + l5] =
                    (_Float16)(O[nt4][rg] * inv_l[rg]);
            }
    }
}

// ---------------- combine split-tile partials: ah = (O0+O1)/(l0+l1) ----------
__global__ __launch_bounds__(256) void combine_k(const float* __restrict__ O_ws,
                                                 const float* __restrict__ l_ws,
                                                 _Float16* __restrict__ ah) {
    const int x = blockIdx.x, h = blockIdx.y, b = blockIdx.z;   // (7,16,2)
    const int tid = threadIdx.x;
    const int d = tid & 127;
    size_t po = (((size_t)(b * NHD + h) * NSPLIT + x) * 2);
    const float* O0 = O_ws + po * 16384;
    const float* O1 = O0 + 16384;
    const float* L0 = l_ws + po * 128;
    const float* L1 = L0 + 128;
    for (int ql = tid >> 7; ql < 128; ql += 2) {
        float l = L0[ql] + L1[ql];
        float o = O0[ql * 128 + d] + O1[ql * 128 + d];
        ah[((size_t)(b * NN + x * 128 + ql)) * HDIM + h * DD + d] = (_Float16)(o / l);
    }
}

// ---------------- mean(V) for row N-1, pass 1: partial sums ----------------
__global__ __launch_bounds__(256) void vsum_k(const _Float16* __restrict__ kvp,
                                              float* __restrict__ vsum) {
    __shared__ float red[16][128];
    const int seg = blockIdx.x, kvh = blockIdx.y, b = blockIdx.z;
    const int tid = threadIdx.x;
    const int jj = tid >> 4, dc = (tid & 15) * 8;
    float acc[8] = {};
    #pragma unroll 4
    for (int j = seg * 256 + jj; j < seg * 256 + 256; j += 16) {
        h8 v = *(const h8*)(kvp + ((size_t)(b * NN + j)) * KVW + 512 + kvh * DD + dc);
        #pragma unroll
        for (int e = 0; e < 8; ++e) acc[e] += (float)v[e];
    }
    #pragma unroll
    for (int e = 0; e < 8; ++e) red[jj][dc + e] = acc[e];
    __syncthreads();
    if (tid < 128) {
        float s = 0.f;
        #pragma unroll
        for (int t = 0; t < 16; ++t) s += red[t][tid];
        atomicAdd(&vsum[(b * KVHD + kvh) * DD + tid], s);
    }
}

// pass 2: write mean into row N-1 for the 4 heads sharing each kv head.
__global__ void fixup_write_k(const float* __restrict__ vsum,
                              _Float16* __restrict__ ah) {
    int b = blockIdx.x >> 2, kvh = blockIdx.x & 3, d = threadIdx.x;  // 128 thr
    float mean = vsum[(b * KVHD + kvh) * DD + d] * (1.0f / NN);
    #pragma unroll
    for (int r = 0; r < 4; ++r) {
        int h = r * 4 + kvh;    // heads with h % 4 == kvh
        ah[((size_t)(b * NN + NN - 1)) * HDIM + h * DD + d] = (_Float16)mean;
    }
}

extern "C" void kernel_launch(void* const* d_in, const int* in_sizes, int n_in,
                              void* d_out, int out_size, void* d_ws, size_t ws_size,
                              hipStream_t stream) {
    const float* tokens = (const float*)d_in[0];
    const float* norm_w = (const float*)d_in[1];
    const float* Wq = (const float*)d_in[2];
    const float* bq = (const float*)d_in[3];
    const float* Wk = (const float*)d_in[4];
    const float* bk = (const float*)d_in[5];
    const float* Wv = (const float*)d_in[6];
    const float* bv = (const float*)d_in[7];
    const float* Wo = (const float*)d_in[8];
    const float* bo = (const float*)d_in[9];
    float* out = (float*)d_out;

    char* ws = (char*)d_ws;
    _Float16* x_h   = (_Float16*)(ws);                        // 16 MB
    _Float16* wq_h  = (_Float16*)(ws + 16777216);             // 8 MB (contiguous with wkv)
    _Float16* wkv_h = (_Float16*)(ws + 25165824);             // 4 MB
    _Float16* wo_h  = (_Float16*)(ws + 29360128);             // 8 MB
    _Float16* q_h   = (_Float16*)(ws + 37752832);             // 16 MB
    _Float16* kv_h  = (_Float16*)(ws + 54530048);             // 8 MB
    _Float16* a_h   = (_Float16*)(ws + 62918656);             // 16 MB
    unsigned short* vt_h = (unsigned short*)(ws + 79695872);  // 4 MB (bf16) -> ends 83890176
    float*    vsum  = (float*)   (ws + 83890176);             // 4 KB
    float*    l_ws  = (float*)   (ws + 83894272);             // 224 KB (448*128 f32)
    float*    bqkv  = (float*)   (ws + 84123648);             // 12 KB  -> ends 84135936
    // O_ws partials (448 pieces * 64 KB = 29,360,128 B) reuse the x_h/wq_h/wkv_h
    // region, which is dead after the merged QKV GEMM; ends exactly at wo_h.
    float*    O_ws  = (float*)(ws);

    rmsnorm_k<<<MTOK, 256, 0, stream>>>(tokens, norm_w, x_h);
    cvtall_k<<<10240, 256, 0, stream>>>(Wq, Wk, Wv, Wo, wq_h, wkv_h, wo_h);
    biascat_k<<<12, 256, 0, stream>>>(bq, bk, bv, bqkv, vsum);

    // merged Q|K|V projection: Bw rows 0..2047 = Wq, 2048..3071 = Wk|Wv (contiguous)
    gemm_bt<2><<<dim3(3072 / 128, MTOK / 128), 256, 0, stream>>>(
        x_h, wq_h, bqkv, (void*)q_h, (void*)kv_h, 3072, HDIM);

    vtrans_k<<<dim3(MTOK / 64, KVHD), 256, 0, stream>>>(kv_h, vt_h);

    attn_k<<<736, 256, 0, stream>>>(q_h, kv_h, vt_h, a_h, O_ws, l_ws);
    combine_k<<<dim3(NSPLIT, NHD, BB), 256, 0, stream>>>(O_ws, l_ws, a_h);
    vsum_k<<<dim3(8, KVHD, BB), 256, 0, stream>>>(kv_h, vsum);
    fixup_write_k<<<BB * KVHD, 128, 0, stream>>>(vsum, a_h);

    gemm_bt<1><<<dim3(HDIM / 128, MTOK / 128), 256, 0, stream>>>(
        a_h, wo_h, bo, (void*)out, nullptr, HDIM, HDIM);
}

// Round 9
// 316.403 us; speedup vs baseline: 1.2036x; 1.2036x over previous
//
#include <hip/hip_runtime.h>

// Problem constants (B,N,HD,NH,KVH fixed by reference)
#define BB   2
#define NN   2048
#define HDIM 2048
#define NHD  16
#define KVHD 4
#define DD   128
#define KVW  1024          // kv buffer width: k[0:512] | v[512:1024]
#define MTOK (BB*NN)       // 4096 token rows
#define NSPLIT 7           // q-tiles 0..6 are j-split into 2 pieces (linear O/l combine)

typedef _Float16 h8 __attribute__((ext_vector_type(8)));
typedef _Float16 h4 __attribute__((ext_vector_type(4)));
typedef float    f4 __attribute__((ext_vector_type(4)));
typedef float    fx16 __attribute__((ext_vector_type(16)));
typedef short    b8 __attribute__((ext_vector_type(8)));   // 8 bf16
typedef unsigned int u4v __attribute__((ext_vector_type(4)));

static __device__ __forceinline__ fx16 mfma32h(h8 a, h8 b, fx16 c) {
    return __builtin_amdgcn_mfma_f32_32x32x16_f16(a, b, c, 0, 0, 0);
}
static __device__ __forceinline__ f4 mfma16(h8 a, h8 b, f4 c) {
    return __builtin_amdgcn_mfma_f32_16x16x32_f16(a, b, c, 0, 0, 0);
}
static __device__ __forceinline__ fx16 mfma32b(b8 a, b8 b, fx16 c) {
    return __builtin_amdgcn_mfma_f32_32x32x16_bf16(a, b, c, 0, 0, 0);
}

// float -> bf16 RTNE (verified byte-exact in the passing kernels).
// NOTE: do NOT substitute v_cvt_pk_bf16_f32 inline asm -- its half-packing
// order on gfx950 differs from the naive assumption (rounds 0/2 failed on it).
static __device__ __forceinline__ unsigned short f2bf(float f) {
    unsigned int u = __float_as_uint(f);
    u += 0x7FFF + ((u >> 16) & 1);
    return (unsigned short)(u >> 16);
}

// async global->LDS, 16B per lane. LDS dst must be wave-uniform base + lane*16.
// Global source address is per-lane (gather) -> we may permute sources freely.
static __device__ __forceinline__ void gload_lds16(const void* g, void* l) {
    __builtin_amdgcn_global_load_lds(
        (const __attribute__((address_space(1))) void*)g,
        (__attribute__((address_space(3))) void*)l, 16, 0, 0);
}

// ---------------- RMSNorm (fp32 in, f16 out) ----------------
__global__ __launch_bounds__(256) void rmsnorm_k(const float* __restrict__ t,
                                                 const float* __restrict__ wn,
                                                 _Float16* __restrict__ xh) {
    const int row = blockIdx.x, tid = threadIdx.x;
    const float* rp = t + (size_t)row * HDIM;
    float4 v[2];
    float ss = 0.f;
    #pragma unroll
    for (int p = 0; p < 2; ++p) {
        float4 x = *(const float4*)(rp + (p * 256 + tid) * 4);
        v[p] = x;
        ss += x.x * x.x + x.y * x.y + x.z * x.z + x.w * x.w;
    }
    #pragma unroll
    for (int off = 32; off; off >>= 1) ss += __shfl_xor(ss, off, 64);
    __shared__ float sred[4];
    if ((tid & 63) == 0) sred[tid >> 6] = ss;
    __syncthreads();
    float rs = rsqrtf((sred[0] + sred[1] + sred[2] + sred[3]) * (1.0f / HDIM)
                      + 1.1920928955078125e-07f);
    _Float16* op = xh + (size_t)row * HDIM;
    #pragma unroll
    for (int p = 0; p < 2; ++p) {
        int base = (p * 256 + tid) * 4;
        float4 w = *(const float4*)(wn + base);
        h4 o;
        o[0] = (_Float16)(v[p].x * rs * w.x);
        o[1] = (_Float16)(v[p].y * rs * w.y);
        o[2] = (_Float16)(v[p].z * rs * w.z);
        o[3] = (_Float16)(v[p].w * rs * w.w);
        *(h4*)(op + base) = o;
    }
}

// ---------------- fused fp32 -> f16 convert of all 4 weight matrices ---------
__global__ __launch_bounds__(256) void cvtall_k(const float* __restrict__ Wq,
                                                const float* __restrict__ Wk,
                                                const float* __restrict__ Wv,
                                                const float* __restrict__ Wo,
                                                _Float16* __restrict__ wq_h,
                                                _Float16* __restrict__ wkv_h,
                                                _Float16* __restrict__ wo_h) {
    int blk = blockIdx.x;
    const float* src; _Float16* dst; int off;
    if (blk < 4096)      { src = Wq; dst = wq_h;               off = blk; }
    else if (blk < 5120) { src = Wk; dst = wkv_h;              off = blk - 4096; }
    else if (blk < 6144) { src = Wv; dst = wkv_h + 512 * HDIM; off = blk - 5120; }
    else                 { src = Wo; dst = wo_h;               off = blk - 6144; }
    int i = off * 1024 + threadIdx.x * 4;
    float4 v = *(const float4*)(src + i);
    h4 o; o[0] = (_Float16)v.x; o[1] = (_Float16)v.y;
    o[2] = (_Float16)v.z; o[3] = (_Float16)v.w;
    *(h4*)(dst + i) = o;
}

// bias concat [bq | bk | bv] (3072) + zero the vsum accumulator (1024 floats)
__global__ void biascat_k(const float* __restrict__ bq, const float* __restrict__ bk,
                          const float* __restrict__ bv,
                          float* __restrict__ bqkv, float* __restrict__ vsum) {
    int i = blockIdx.x * 256 + threadIdx.x;   // 3072 total
    bqkv[i] = (i < 2048) ? bq[i] : (i < 2560) ? bk[i - 2048] : bv[i - 2560];
    if (i < 1024) vsum[i] = 0.f;
}

// ---------------- V transpose + f16->bf16: kv V-part -> vt[b][kvh][d][pi(N)] ---
// Token column index has bits 2<->3 swapped (involution). PV's 32x32 A-frag
// k-slot s then aligns with the lane-local rows of the 32x32 QK^T output:
// pa[ks] element e = P(reg 8*ks+e) -- P never leaves registers in attn_k.
__global__ __launch_bounds__(256) void vtrans_k(const _Float16* __restrict__ kv,
                                                unsigned short* __restrict__ vt) {
    const int tid = threadIdx.x;
    const int tok = blockIdx.x * 64 + (tid & 63);
    const int kvh = blockIdx.y;
    const int d0 = (tid >> 6) * 32;
    const int b = tok >> 11, n = tok & (NN - 1);
    const int n2 = (n & ~12) | ((n & 4) << 1) | ((n & 8) >> 1);  // swap bits 2,3
    const _Float16* src = kv + (size_t)tok * KVW + 512 + kvh * DD + d0;
    unsigned short* dstb = vt + ((size_t)(b * KVHD + kvh) * DD) * NN + n2;
    #pragma unroll
    for (int u = 0; u < 4; ++u) {
        h8 v = *(const h8*)(src + u * 8);
        #pragma unroll
        for (int e = 0; e < 8; ++e)
            dstb[(size_t)(d0 + u * 8 + e) * NN] = f2bf((float)v[e]);
    }
}

// ---------------- GEMM  C[M,Nout] = A[M,K] * Bw[Nout,K]^T + bias ----------------
// 128x128 tile, 256 thr (4 waves, 2x2), BK=64, global_load_lds x16,
// XOR-swizzled LDS chunks (conflict-free b128 reads).
// MODE 1: f32 out; MODE 2: split out (col<2048 -> Cout f16 w2048,
// else -> Cout2 f16 w1024). Split boundary is 128-tile-aligned => block-uniform.
template <int MODE>
__global__ __launch_bounds__(256, 2) void gemm_bt(const _Float16* __restrict__ A,
                                                  const _Float16* __restrict__ Bw,
                                                  const float* __restrict__ bias,
                                                  void* __restrict__ Cout,
                                                  void* __restrict__ Cout2,
                                                  int Ndim, int K) {
    __shared__ _Float16 sA[128 * 64];
    __shared__ _Float16 sB[128 * 64];
    const int tid = threadIdx.x;
    const int lane = tid & 63, w = tid >> 6;
    const int ln = lane & 15, quad = lane >> 4;
    const int wm = w >> 1, wn = w & 1;
    const int m0 = blockIdx.y * 128, n0 = blockIdx.x * 128;

    f4 acc[4][4] = {};
    for (int k0 = 0; k0 < K; k0 += 64) {
        #pragma unroll
        for (int it = 0; it < 4; ++it) {
            int chunk = it * 256 + tid;            // 1024 chunks of 8 halves
            int row = chunk >> 3, p = chunk & 7;
            int c = p ^ (row & 7);                 // logical source chunk
            gload_lds16(A + (size_t)(m0 + row) * K + k0 + c * 8, sA + chunk * 8);
            gload_lds16(Bw + (size_t)(n0 + row) * K + k0 + c * 8, sB + chunk * 8);
        }
        __syncthreads();
        #pragma unroll
        for (int kk = 0; kk < 2; ++kk) {
            h8 af[4], bf[4];
            #pragma unroll
            for (int mt = 0; mt < 4; ++mt)
                af[mt] = *(const h8*)&sA[(wm * 64 + mt * 16 + ln) * 64 +
                                         (((kk * 4 + quad) ^ (ln & 7)) << 3)];
            #pragma unroll
            for (int nt = 0; nt < 4; ++nt)
                bf[nt] = *(const h8*)&sB[(wn * 64 + nt * 16 + ln) * 64 +
                                         (((kk * 4 + quad) ^ (ln & 7)) << 3)];
            #pragma unroll
            for (int mt = 0; mt < 4; ++mt)
                #pragma unroll
                for (int nt = 0; nt < 4; ++nt)
                    acc[mt][nt] = mfma16(af[mt], bf[nt], acc[mt][nt]);
        }
        __syncthreads();
    }
    #pragma unroll
    for (int mt = 0; mt < 4; ++mt) {
        int rowb = m0 + wm * 64 + mt * 16 + quad * 4;   // C: row = quad*4+reg
        #pragma unroll
        for (int nt = 0; nt < 4; ++nt) {
            int col = n0 + wn * 64 + nt * 16 + ln;      // C: col = lane&15
            float bv = bias[col];
            #pragma unroll
            for (int r = 0; r < 4; ++r) {
                float v = acc[mt][nt][r] + bv;
                if (MODE == 1)
                    ((float*)Cout)[(size_t)(rowb + r) * Ndim + col] = v;
                else {  // MODE 2: split q|kv
                    if (n0 < 2048)
                        ((_Float16*)Cout)[(size_t)(rowb + r) * HDIM + col] = (_Float16)v;
                    else
                        ((_Float16*)Cout2)[(size_t)(rowb + r) * KVW + (col - 2048)] = (_Float16)v;
                }
            }
        }
    }
}

// ---------------- attn piece table, GLOBALLY sorted by length (LPT) ----------
// code = x | (p<<8) | (split<<16). Lengths (64-j iters) desc:
// 18,16,16,16,15,15,14,14,14,13,13,12,12,12,11,11,10,10,10,8,6,4,2
__device__ __constant__ int piece_tab[23] = {
    7,                      // c0  whole x=7   len 18
    0x10000, 0x10100,       // c1,2 split x=0  len 16
    8,                      // c3  whole x=8   len 16
    0x10001, 0x10101,       // c4,5 split x=1  len 15
    0x10002, 0x10102,       // c6,7 split x=2  len 14
    9,                      // c8  whole x=9   len 14
    0x10003, 0x10103,       // c9,10 split x=3 len 13
    0x10004, 0x10104,       // c11,12 split x=4 len 12
    10,                     // c13 whole x=10  len 12
    0x10005, 0x10105,       // c14,15 split x=5 len 11
    0x10006, 0x10106,       // c16,17 split x=6 len 10
    11, 12, 13, 14, 15      // c18..22 whole   len 10,8,6,4,2
};

// ---------------- Flash attention, inverted-causal (attend j > i) ----------------
// No-max softmax (scores bounded => P=exp(s) exact in fp32/bf16 range) => O and l
// are LINEAR in the j-range: split pieces sum with no rescaling (combine_k).
// QK^T via 32x32x16 f16 MFMA, swapped operands (A=K, B=Q -> D[m=j][n=q=l5]);
// V columns bit-2<->3-swapped (vtrans_k) => P packed in register order, no LDS.
// BN=64, 64KB LDS, 2 blocks/CU -- MUST stay at 2 blocks/CU: round 7 (BN=32,
// 4-5 blocks/CU) tripled HBM FETCH (19->114 MB) by thrashing the 4MB XCD L2
// with 2.2x the concurrent KV stream diversity; attn is L2-locality-bound.
// XOR swizzles carry row-high-bit terms (^(row>>3)&3 on both stage source and
// read -- the involution round 7 PROVED zeroes SQ_LDS_BANK_CONFLICT): lanes
// 8/16/24 apart previously aliased (row strides are 0 mod 128B) -> 4-way.
// LPT 1-D dispatch (class = blockIdx.x>>5 desc length, hb = blockIdx.x&31).
__global__ __launch_bounds__(256, 2) void attn_k(const _Float16* __restrict__ qh,
                                                 const _Float16* __restrict__ kvp,
                                                 const unsigned short* __restrict__ vt,
                                                 _Float16* __restrict__ ah,
                                                 float* __restrict__ O_ws,
                                                 float* __restrict__ l_ws) {
    __shared__ _Float16 s_k[2][64 * 128];        // K tiles [j][d] f16, 16-chunk xor
    __shared__ unsigned short s_v[2][128 * 64];  // V^T tiles [d][j'] bf16, 8-chunk xor
    const int tid = threadIdx.x;
    const int lane = tid & 63, w = tid >> 6;     // 4 waves
    const int l5 = lane & 31, hi = lane >> 5;
    const int idx = blockIdx.x;                  // 736 = 23 classes x 32 (h,b)
    const int hb = idx & 31;
    const int h = hb & 15, b = hb >> 4;
    const int code = piece_tab[idx >> 5];
    const int x = code & 255, p = (code >> 8) & 1;
    const bool is_split = (code >> 16) & 1;
    int jlo, jhi;
    if (is_split) { int len = 16 - x; jlo = 2 * x + p * len; jhi = jlo + len; }
    else          { jlo = 2 * x; jhi = 32; }
    const int i0 = x * 128;
    const int kvh = h & 3;                       // head h uses kv head h % KVH
    const int qg = i0 + w * 32 + l5;             // this lane's q row (in batch)

    // Q fragments: B[n=q=l5][k=hi*8+e]; chunk kc covers d = kc*16 + hi*8 + e
    h8 qf[8];
    {
        const _Float16* qrow =
            qh + ((size_t)(b * NN + qg)) * HDIM + h * DD;
        #pragma unroll
        for (int kc = 0; kc < 8; ++kc)
            qf[kc] = *(const h8*)(qrow + kc * 16 + hi * 8);
    }

    b8 ones;
    #pragma unroll
    for (int e = 0; e < 8; ++e) ones[e] = (short)0x3F80;   // bf16 1.0

    fx16 O[4] = {};   // D[m=q(32)][n=d 32-block], 4 d-blocks
    fx16 OS = {};     // l via ones-column (all cols equal)

    // stage 64-wide j-tile jt into buffer bufi (256 thr, 4+4 chunks each)
    auto stage = [&](int jt, int bufi) {
        const int j0s = jt * 64;
        #pragma unroll
        for (int itr = 0; itr < 4; ++itr) {      // K: 64 rows x 16 chunks
            int chunk = itr * 256 + tid;
            int jj = chunk >> 4, pp = chunk & 15;
            int c = pp ^ (jj & 15) ^ ((jj >> 3) & 3);
            gload_lds16(kvp + ((size_t)(b * NN + j0s + jj)) * KVW + kvh * DD + c * 8,
                        &s_k[bufi][chunk * 8]);
        }
        #pragma unroll
        for (int itr = 0; itr < 4; ++itr) {      // V^T: 128 rows x 8 chunks
            int chunk = itr * 256 + tid;
            int d = chunk >> 3, pp = chunk & 7;
            int c = pp ^ (d & 7) ^ ((d >> 3) & 3);
            gload_lds16(vt + ((size_t)(b * KVHD + kvh) * DD + d) * NN + j0s + c * 8,
                        &s_v[bufi][chunk * 8]);
        }
    };

    stage(jlo, 0);
    for (int jt = jlo; jt < jhi; ++jt) {
        const int j0 = jt * 64;
        const int cur = (jt - jlo) & 1;
        __syncthreads();                           // buf[cur] ready
        if (jt + 1 < jhi) stage(jt + 1, cur ^ 1);  // prefetch during compute

        // S^T = K Q^T : two 32-j blocks; A=K-frag (row l5 / 32+l5), B=qf
        fx16 sc0 = {}, sc1 = {};
        #pragma unroll
        for (int kc = 0; kc < 8; ++kc) {
            int cs = ((kc * 2 + hi) ^ (l5 & 15) ^ ((l5 >> 3) & 3)) << 3;
            h8 k0 = *(const h8*)&s_k[cur][l5 * 128 + cs];
            h8 k1 = *(const h8*)&s_k[cur][(32 + l5) * 128 + cs];
            sc0 = mfma32h(k0, qf[kc], sc0);
            sc1 = mfma32h(k1, qf[kc], sc1);
        }

        const bool need_mask = (jt < 2 * x + 2);   // masked iters are in piece 0
        #pragma unroll
        for (int jb = 0; jb < 2; ++jb) {
            const fx16& sc = jb ? sc1 : sc0;
            // mask + exp + bf16 pack (verified byte order), in register order
            unsigned int pwod[8];
            #pragma unroll
            for (int pr = 0; pr < 8; ++pr) {
                float s0 = sc[2 * pr], s1 = sc[2 * pr + 1];
                if (need_mask) {
                    int rg0 = 2 * pr;              // even: rg0&3 in {0,2} -> jg1=jg0+1
                    int jg0 = j0 + jb * 32 + (rg0 & 3) + 8 * (rg0 >> 2) + 4 * hi;
                    if (jg0 <= qg) s0 = -1e9f;     // faithful inverted mask
                    if (jg0 + 1 <= qg) s1 = -1e9f;
                }
                pwod[pr] = (unsigned int)f2bf(__expf(s0)) |
                           ((unsigned int)f2bf(__expf(s1)) << 16);
            }
            u4v w0v = {pwod[0], pwod[1], pwod[2], pwod[3]};
            u4v w1v = {pwod[4], pwod[5], pwod[6], pwod[7]};
            b8 pa0 = __builtin_bit_cast(b8, w0v);  // k-slots 0..15  (regs 0..7)
            b8 pa1 = __builtin_bit_cast(b8, w1v);  // k-slots 16..31 (regs 8..15)

            // O += P V ; OS += P 1   (A[m=q=l5][k], B[n=d][k=j'])
            #pragma unroll
            for (int ks = 0; ks < 2; ++ks) {
                b8 pa = ks ? pa1 : pa0;
                #pragma unroll
                for (int dblk = 0; dblk < 4; ++dblk) {
                    b8 bv = *(const b8*)&s_v[cur][(dblk * 32 + l5) * 64 +
                             (((jb * 4 + ks * 2 + hi) ^ (l5 & 7) ^ ((l5 >> 3) & 3)) << 3)];
                    O[dblk] = mfma32b(pa, bv, O[dblk]);
                }
                OS = mfma32b(pa, ones, OS);
            }
        }
    }

    // epilogue. 32x32 C-layout: col=l5=d-local, row=(rg&3)+8*(rg>>2)+4*hi=q-local.
    if (is_split) {
        // write f32 partials (no divide) for combine_k
        size_t po = (((size_t)(b * NHD + h) * NSPLIT + x) * 2 + p);
        float* Op = O_ws + po * 16384;
        float* Lp = l_ws + po * 128;
        #pragma unroll
        for (int nt4 = 0; nt4 < 4; ++nt4)
            #pragma unroll
            for (int rg = 0; rg < 16; ++rg) {
                int q = (rg & 3) + 8 * (rg >> 2) + 4 * hi;
                Op[(w * 32 + q) * 128 + nt4 * 32 + l5] = O[nt4][rg];
            }
        if (l5 == 0) {
            #pragma unroll
            for (int rg = 0; rg < 16; ++rg) {
                int q = (rg & 3) + 8 * (rg >> 2) + 4 * hi;
                Lp[w * 32 + q] = OS[rg];
            }
        }
    } else {
        // Row N-1: l=0 -> NaN, overwritten by fixup kernels.
        float inv_l[16];
        #pragma unroll
        for (int rg = 0; rg < 16; ++rg) inv_l[rg] = 1.0f / OS[rg];
        #pragma unroll
        for (int nt4 = 0; nt4 < 4; ++nt4)
            #pragma unroll
            for (int rg = 0; rg < 16; ++rg) {
                int q = (rg & 3) + 8 * (rg >> 2) + 4 * hi;
                ah[((size_t)(b * NN + i0 + w * 32 + q)) * HDIM + h * DD + nt4 * 32 + l5] =
                    (_Float16)(O[nt4][rg] * inv_l[rg]);
            }
    }
}

// ---------------- combine split-tile partials: ah = (O0+O1)/(l0+l1) ----------
__global__ __launch_bounds__(256) void combine_k(const float* __restrict__ O_ws,
                                                 const float* __restrict__ l_ws,
                                                 _Float16* __restrict__ ah) {
    const int x = blockIdx.x, h = blockIdx.y, b = blockIdx.z;   // (7,16,2)
    const int tid = threadIdx.x;
    const int d = tid & 127;
    size_t po = (((size_t)(b * NHD + h) * NSPLIT + x) * 2);
    const float* O0 = O_ws + po * 16384;
    const float* O1 = O0 + 16384;
    const float* L0 = l_ws + po * 128;
    const float* L1 = L0 + 128;
    for (int ql = tid >> 7; ql < 128; ql += 2) {
        float l = L0[ql] + L1[ql];
        float o = O0[ql * 128 + d] + O1[ql * 128 + d];
        ah[((size_t)(b * NN + x * 128 + ql)) * HDIM + h * DD + d] = (_Float16)(o / l);
    }
}

// ---------------- mean(V) for row N-1, pass 1: partial sums ----------------
__global__ __launch_bounds__(256) void vsum_k(const _Float16* __restrict__ kvp,
                                              float* __restrict__ vsum) {
    __shared__ float red[16][128];
    const int seg = blockIdx.x, kvh = blockIdx.y, b = blockIdx.z;
    const int tid = threadIdx.x;
    const int jj = tid >> 4, dc = (tid & 15) * 8;
    float acc[8] = {};
    #pragma unroll 4
    for (int j = seg * 256 + jj; j < seg * 256 + 256; j += 16) {
        h8 v = *(const h8*)(kvp + ((size_t)(b * NN + j)) * KVW + 512 + kvh * DD + dc);
        #pragma unroll
        for (int e = 0; e < 8; ++e) acc[e] += (float)v[e];
    }
    #pragma unroll
    for (int e = 0; e < 8; ++e) red[jj][dc + e] = acc[e];
    __syncthreads();
    if (tid < 128) {
        float s = 0.f;
        #pragma unroll
        for (int t = 0; t < 16; ++t) s += red[t][tid];
        atomicAdd(&vsum[(b * KVHD + kvh) * DD + tid], s);
    }
}

// pass 2: write mean into row N-1 for the 4 heads sharing each kv head.
__global__ void fixup_write_k(const float* __restrict__ vsum,
                              _Float16* __restrict__ ah) {
    int b = blockIdx.x >> 2, kvh = blockIdx.x & 3, d = threadIdx.x;  // 128 thr
    float mean = vsum[(b * KVHD + kvh) * DD + d] * (1.0f / NN);
    #pragma unroll
    for (int r = 0; r < 4; ++r) {
        int h = r * 4 + kvh;    // heads with h % 4 == kvh
        ah[((size_t)(b * NN + NN - 1)) * HDIM + h * DD + d] = (_Float16)mean;
    }
}

extern "C" void kernel_launch(void* const* d_in, const int* in_sizes, int n_in,
                              void* d_out, int out_size, void* d_ws, size_t ws_size,
                              hipStream_t stream) {
    const float* tokens = (const float*)d_in[0];
    const float* norm_w = (const float*)d_in[1];
    const float* Wq = (const float*)d_in[2];
    const float* bq = (const float*)d_in[3];
    const float* Wk = (const float*)d_in[4];
    const float* bk = (const float*)d_in[5];
    const float* Wv = (const float*)d_in[6];
    const float* bv = (const float*)d_in[7];
    const float* Wo = (const float*)d_in[8];
    const float* bo = (const float*)d_in[9];
    float* out = (float*)d_out;

    char* ws = (char*)d_ws;
    _Float16* x_h   = (_Float16*)(ws);                        // 16 MB
    _Float16* wq_h  = (_Float16*)(ws + 16777216);             // 8 MB (contiguous with wkv)
    _Float16* wkv_h = (_Float16*)(ws + 25165824);             // 4 MB
    _Float16* wo_h  = (_Float16*)(ws + 29360128);             // 8 MB
    _Float16* q_h   = (_Float16*)(ws + 37752832);             // 16 MB
    _Float16* kv_h  = (_Float16*)(ws + 54530048);             // 8 MB
    _Float16* a_h   = (_Float16*)(ws + 62918656);             // 16 MB
    unsigned short* vt_h = (unsigned short*)(ws + 79695872);  // 4 MB (bf16) -> ends 83890176
    float*    vsum  = (float*)   (ws + 83890176);             // 4 KB
    float*    l_ws  = (float*)   (ws + 83894272);             // 224 KB (448*128 f32)
    float*    bqkv  = (float*)   (ws + 84123648);             // 12 KB  -> ends 84135936
    // O_ws partials (448 pieces * 64 KB = 29,360,128 B) reuse the x_h/wq_h/wkv_h
    // region, which is dead after the merged QKV GEMM; ends exactly at wo_h.
    float*    O_ws  = (float*)(ws);

    rmsnorm_k<<<MTOK, 256, 0, stream>>>(tokens, norm_w, x_h);
    cvtall_k<<<10240, 256, 0, stream>>>(Wq, Wk, Wv, Wo, wq_h, wkv_h, wo_h);
    biascat_k<<<12, 256, 0, stream>>>(bq, bk, bv, bqkv, vsum);

    // merged Q|K|V projection: Bw rows 0..2047 = Wq, 2048..3071 = Wk|Wv (contiguous)
    gemm_bt<2><<<dim3(3072 / 128, MTOK / 128), 256, 0, stream>>>(
        x_h, wq_h, bqkv, (void*)q_h, (void*)kv_h, 3072, HDIM);

    vtrans_k<<<dim3(MTOK / 64, KVHD), 256, 0, stream>>>(kv_h, vt_h);

    attn_k<<<736, 256, 0, stream>>>(q_h, kv_h, vt_h, a_h, O_ws, l_ws);
    combine_k<<<dim3(NSPLIT, NHD, BB), 256, 0, stream>>>(O_ws, l_ws, a_h);
    vsum_k<<<dim3(8, KVHD, BB), 256, 0, stream>>>(kv_h, vsum);
    fixup_write_k<<<BB * KVHD, 128, 0, stream>>>(vsum, a_h);

    gemm_bt<1><<<dim3(HDIM / 128, MTOK / 128), 256, 0, stream>>>(
        a_h, wo_h, bo, (void*)out, nullptr, HDIM, HDIM);
}

// Round 10
// 299.375 us; speedup vs baseline: 1.2720x; 1.0569x over previous
//
#include <hip/hip_runtime.h>

// Problem constants (B,N,HD,NH,KVH fixed by reference)
#define BB   2
#define NN   2048
#define HDIM 2048
#define NHD  16
#define KVHD 4
#define DD   128
#define KVW  1024          // kv buffer width: k[0:512] | v[512:1024] (V half now unused)
#define MTOK (BB*NN)       // 4096 token rows
#define NSPLIT 7           // q-tiles 0..6 are j-split into 2 pieces (linear O/l combine)

typedef _Float16 h8 __attribute__((ext_vector_type(8)));
typedef _Float16 h4 __attribute__((ext_vector_type(4)));
typedef float    f4 __attribute__((ext_vector_type(4)));
typedef float    fx16 __attribute__((ext_vector_type(16)));
typedef short    b8 __attribute__((ext_vector_type(8)));   // 8 bf16
typedef unsigned int u4v __attribute__((ext_vector_type(4)));

static __device__ __forceinline__ fx16 mfma32h(h8 a, h8 b, fx16 c) {
    return __builtin_amdgcn_mfma_f32_32x32x16_f16(a, b, c, 0, 0, 0);
}
static __device__ __forceinline__ f4 mfma16(h8 a, h8 b, f4 c) {
    return __builtin_amdgcn_mfma_f32_16x16x32_f16(a, b, c, 0, 0, 0);
}
static __device__ __forceinline__ fx16 mfma32b(b8 a, b8 b, fx16 c) {
    return __builtin_amdgcn_mfma_f32_32x32x16_bf16(a, b, c, 0, 0, 0);
}

// float -> bf16 RTNE (verified byte-exact in the passing kernels).
// NOTE: do NOT substitute v_cvt_pk_bf16_f32 inline asm -- its half-packing
// order on gfx950 differs from the naive assumption (rounds 0/2 failed on it).
static __device__ __forceinline__ unsigned short f2bf(float f) {
    unsigned int u = __float_as_uint(f);
    u += 0x7FFF + ((u >> 16) & 1);
    return (unsigned short)(u >> 16);
}

// async global->LDS, 16B per lane. LDS dst must be wave-uniform base + lane*16.
// Global source address is per-lane (gather) -> we may permute sources freely.
static __device__ __forceinline__ void gload_lds16(const void* g, void* l) {
    __builtin_amdgcn_global_load_lds(
        (const __attribute__((address_space(1))) void*)g,
        (__attribute__((address_space(3))) void*)l, 16, 0, 0);
}

// ---------------- fused prep: RMSNorm | weight cvt | bias concat + vsum zero --
// blocks [0,4096): rmsnorm row; [4096,14336): weight f32->f16 (Wq|Wk|Wv|Wo);
// [14336,14348): bqkv concat (3072) + vsum zero (1024).
__global__ __launch_bounds__(256) void prep_k(
    const float* __restrict__ tokens, const float* __restrict__ wn,
    const float* __restrict__ Wq, const float* __restrict__ Wk,
    const float* __restrict__ Wv, const float* __restrict__ Wo,
    const float* __restrict__ bq, const float* __restrict__ bk,
    const float* __restrict__ bv,
    _Float16* __restrict__ xh, _Float16* __restrict__ wq_h,
    _Float16* __restrict__ wkv_h, _Float16* __restrict__ wo_h,
    float* __restrict__ bqkv, float* __restrict__ vsum) {
    const int tid = threadIdx.x;
    int blk = blockIdx.x;
    if (blk < MTOK) {                       // ---- RMSNorm (fp32 in, f16 out)
        __shared__ float sred[4];
        const float* rp = tokens + (size_t)blk * HDIM;
        float4 v[2];
        float ss = 0.f;
        #pragma unroll
        for (int p = 0; p < 2; ++p) {
            float4 x = *(const float4*)(rp + (p * 256 + tid) * 4);
            v[p] = x;
            ss += x.x * x.x + x.y * x.y + x.z * x.z + x.w * x.w;
        }
        #pragma unroll
        for (int off = 32; off; off >>= 1) ss += __shfl_xor(ss, off, 64);
        if ((tid & 63) == 0) sred[tid >> 6] = ss;
        __syncthreads();
        float rs = rsqrtf((sred[0] + sred[1] + sred[2] + sred[3]) * (1.0f / HDIM)
                          + 1.1920928955078125e-07f);
        _Float16* op = xh + (size_t)blk * HDIM;
        #pragma unroll
        for (int p = 0; p < 2; ++p) {
            int base = (p * 256 + tid) * 4;
            float4 w = *(const float4*)(wn + base);
            h4 o;
            o[0] = (_Float16)(v[p].x * rs * w.x);
            o[1] = (_Float16)(v[p].y * rs * w.y);
            o[2] = (_Float16)(v[p].z * rs * w.z);
            o[3] = (_Float16)(v[p].w * rs * w.w);
            *(h4*)(op + base) = o;
        }
        return;
    }
    blk -= MTOK;
    if (blk < 10240) {                      // ---- weight convert
        const float* src; _Float16* dst; int off;
        if (blk < 4096)      { src = Wq; dst = wq_h;               off = blk; }
        else if (blk < 5120) { src = Wk; dst = wkv_h;              off = blk - 4096; }
        else if (blk < 6144) { src = Wv; dst = wkv_h + 512 * HDIM; off = blk - 5120; }
        else                 { src = Wo; dst = wo_h;               off = blk - 6144; }
        int i = off * 1024 + tid * 4;
        float4 v = *(const float4*)(src + i);
        h4 o; o[0] = (_Float16)v.x; o[1] = (_Float16)v.y;
        o[2] = (_Float16)v.z; o[3] = (_Float16)v.w;
        *(h4*)(dst + i) = o;
        return;
    }
    blk -= 10240;                           // ---- bias concat + vsum zero
    int i = blk * 256 + tid;                // 3072 total
    bqkv[i] = (i < 2048) ? bq[i] : (i < 2560) ? bk[i - 2048] : bv[i - 2560];
    if (i < 1024) vsum[i] = 0.f;
}

// ---------------- GEMM  C[M,Nout] = A[M,K] * Bw[Nout,K]^T + bias ----------------
// 128x128 tile, 256 thr (4 waves, 2x2), BK=64, global_load_lds x16,
// XOR-swizzled LDS chunks (conflict-free b128 reads).
// MODE 1: f32 out. MODE 2 (QKV, fused): col<2048 -> q_h f16; col in [2048,2560)
// -> kv_h K-region f16; col>=2560 (V) -> vt bf16 TRANSPOSED (token col bit-2<->3
// swapped, replacing vtrans_k; f32->f16->bf16 double-rounding kept bit-identical
// to the old path) + vsum atomicAdd of the f16-rounded values (replacing vsum_k;
// quad shfl-reduce -> 1 atomic per 64 tokens). All branches 128-tile-aligned =>
// block-uniform.
template <int MODE>
__global__ __launch_bounds__(256, 2) void gemm_bt(const _Float16* __restrict__ A,
                                                  const _Float16* __restrict__ Bw,
                                                  const float* __restrict__ bias,
                                                  void* __restrict__ Cout,
                                                  void* __restrict__ Cout2,
                                                  unsigned short* __restrict__ vt,
                                                  float* __restrict__ vsum,
                                                  int Ndim, int K) {
    __shared__ _Float16 sA[128 * 64];
    __shared__ _Float16 sB[128 * 64];
    const int tid = threadIdx.x;
    const int lane = tid & 63, w = tid >> 6;
    const int ln = lane & 15, quad = lane >> 4;
    const int wm = w >> 1, wn = w & 1;
    const int m0 = blockIdx.y * 128, n0 = blockIdx.x * 128;

    f4 acc[4][4] = {};
    for (int k0 = 0; k0 < K; k0 += 64) {
        #pragma unroll
        for (int it = 0; it < 4; ++it) {
            int chunk = it * 256 + tid;            // 1024 chunks of 8 halves
            int row = chunk >> 3, p = chunk & 7;
            int c = p ^ (row & 7);                 // logical source chunk
            gload_lds16(A + (size_t)(m0 + row) * K + k0 + c * 8, sA + chunk * 8);
            gload_lds16(Bw + (size_t)(n0 + row) * K + k0 + c * 8, sB + chunk * 8);
        }
        __syncthreads();
        #pragma unroll
        for (int kk = 0; kk < 2; ++kk) {
            h8 af[4], bf[4];
            #pragma unroll
            for (int mt = 0; mt < 4; ++mt)
                af[mt] = *(const h8*)&sA[(wm * 64 + mt * 16 + ln) * 64 +
                                         (((kk * 4 + quad) ^ (ln & 7)) << 3)];
            #pragma unroll
            for (int nt = 0; nt < 4; ++nt)
                bf[nt] = *(const h8*)&sB[(wn * 64 + nt * 16 + ln) * 64 +
                                         (((kk * 4 + quad) ^ (ln & 7)) << 3)];
            #pragma unroll
            for (int mt = 0; mt < 4; ++mt)
                #pragma unroll
                for (int nt = 0; nt < 4; ++nt)
                    acc[mt][nt] = mfma16(af[mt], bf[nt], acc[mt][nt]);
        }
        __syncthreads();
    }

    if (MODE == 2 && n0 >= 2560) {
        // V blocks: transpose-write vt + vsum partial sums (kv_h V-region dead)
        #pragma unroll
        for (int nt = 0; nt < 4; ++nt) {
            int col = n0 + wn * 64 + nt * 16 + ln;
            int vd = col - 2560, kvh = vd >> 7, d = vd & 127;
            float bvb = bias[col];
            float vs = 0.f;
            #pragma unroll
            for (int mt = 0; mt < 4; ++mt) {
                int rowb = m0 + wm * 64 + mt * 16 + quad * 4;
                #pragma unroll
                for (int r = 0; r < 4; ++r) {
                    _Float16 hv = (_Float16)(acc[mt][nt][r] + bvb);
                    float fv = (float)hv;
                    int token = rowb + r;
                    int n = token & (NN - 1);
                    int n2 = (n & ~12) | ((n & 4) << 1) | ((n & 8) >> 1);
                    vt[((size_t)((token >> 11) * KVHD + kvh) * DD + d) * NN + n2] =
                        f2bf(fv);
                    vs += fv;
                }
            }
            vs += __shfl_xor(vs, 16, 64);
            vs += __shfl_xor(vs, 32, 64);   // sum over 4 quads = 64 tokens
            if (quad == 0)
                atomicAdd(&vsum[((size_t)(m0 >> 11) * KVHD + kvh) * DD + d], vs);
        }
        return;
    }

    #pragma unroll
    for (int mt = 0; mt < 4; ++mt) {
        int rowb = m0 + wm * 64 + mt * 16 + quad * 4;   // C: row = quad*4+reg
        #pragma unroll
        for (int nt = 0; nt < 4; ++nt) {
            int col = n0 + wn * 64 + nt * 16 + ln;      // C: col = lane&15
            float bv = bias[col];
            #pragma unroll
            for (int r = 0; r < 4; ++r) {
                float v = acc[mt][nt][r] + bv;
                if (MODE == 1)
                    ((float*)Cout)[(size_t)(rowb + r) * Ndim + col] = v;
                else {  // MODE 2, q or K region
                    if (n0 < 2048)
                        ((_Float16*)Cout)[(size_t)(rowb + r) * HDIM + col] = (_Float16)v;
                    else
                        ((_Float16*)Cout2)[(size_t)(rowb + r) * KVW + (col - 2048)] = (_Float16)v;
                }
            }
        }
    }
}

// ---------------- attn piece table, GLOBALLY sorted by length (LPT) ----------
// code = x | (p<<8) | (split<<16). Lengths (64-j iters) desc:
// 18,16,16,16,15,15,14,14,14,13,13,12,12,12,11,11,10,10,10,8,6,4,2
__device__ __constant__ int piece_tab[23] = {
    7,                      // c0  whole x=7   len 18
    0x10000, 0x10100,       // c1,2 split x=0  len 16
    8,                      // c3  whole x=8   len 16
    0x10001, 0x10101,       // c4,5 split x=1  len 15
    0x10002, 0x10102,       // c6,7 split x=2  len 14
    9,                      // c8  whole x=9   len 14
    0x10003, 0x10103,       // c9,10 split x=3 len 13
    0x10004, 0x10104,       // c11,12 split x=4 len 12
    10,                     // c13 whole x=10  len 12
    0x10005, 0x10105,       // c14,15 split x=5 len 11
    0x10006, 0x10106,       // c16,17 split x=6 len 10
    11, 12, 13, 14, 15      // c18..22 whole   len 10,8,6,4,2
};

// ---------------- Flash attention, inverted-causal (attend j > i) ----------------
// No-max softmax (scores bounded => P=exp(s) exact in fp32/bf16 range) => O and l
// are LINEAR in the j-range: split pieces sum with no rescaling (combine_k).
// QK^T via 32x32x16 f16 MFMA, swapped operands (A=K, B=Q -> D[m=j][n=q=l5]);
// V columns bit-2<->3-swapped => P packed in register order, no LDS round-trip.
// BN=64, 64KB LDS, 2 blocks/CU -- MUST stay at 2 blocks/CU (round 7: 4-5
// blocks/CU tripled HBM FETCH by thrashing the 4MB XCD L2; L2-locality-bound).
// XOR swizzles carry row-high-bit terms -- round 7/8 PROVED SQ_LDS_BANK_CONFLICT
// = 0 with this involution (on both stage source and read). Round 8 also proved
// conflicts were NOT the critical path (time unchanged) -- kernel is stall-bound.
// LPT 1-D dispatch (class = blockIdx.x>>5 desc length, hb = blockIdx.x&31).
__global__ __launch_bounds__(256, 2) void attn_k(const _Float16* __restrict__ qh,
                                                 const _Float16* __restrict__ kvp,
                                                 const unsigned short* __restrict__ vt,
                                                 _Float16* __restrict__ ah,
                                                 float* __restrict__ O_ws,
                                                 float* __restrict__ l_ws) {
    __shared__ _Float16 s_k[2][64 * 128];        // K tiles [j][d] f16, 16-chunk xor
    __shared__ unsigned short s_v[2][128 * 64];  // V^T tiles [d][j'] bf16, 8-chunk xor
    const int tid = threadIdx.x;
    const int lane = tid & 63, w = tid >> 6;     // 4 waves
    const int l5 = lane & 31, hi = lane >> 5;
    const int idx = blockIdx.x;                  // 736 = 23 classes x 32 (h,b)
    const int hb = idx & 31;
    const int h = hb & 15, b = hb >> 4;
    const int code = piece_tab[idx >> 5];
    const int x = code & 255, p = (code >> 8) & 1;
    const bool is_split = (code >> 16) & 1;
    int jlo, jhi;
    if (is_split) { int len = 16 - x; jlo = 2 * x + p * len; jhi = jlo + len; }
    else          { jlo = 2 * x; jhi = 32; }
    const int i0 = x * 128;
    const int kvh = h & 3;                       // head h uses kv head h % KVH
    const int qg = i0 + w * 32 + l5;             // this lane's q row (in batch)

    // Q fragments: B[n=q=l5][k=hi*8+e]; chunk kc covers d = kc*16 + hi*8 + e
    h8 qf[8];
    {
        const _Float16* qrow =
            qh + ((size_t)(b * NN + qg)) * HDIM + h * DD;
        #pragma unroll
        for (int kc = 0; kc < 8; ++kc)
            qf[kc] = *(const h8*)(qrow + kc * 16 + hi * 8);
    }

    b8 ones;
    #pragma unroll
    for (int e = 0; e < 8; ++e) ones[e] = (short)0x3F80;   // bf16 1.0

    fx16 O[4] = {};   // D[m=q(32)][n=d 32-block], 4 d-blocks
    fx16 OS = {};     // l via ones-column (all cols equal)

    // stage 64-wide j-tile jt into buffer bufi (256 thr, 4+4 chunks each)
    auto stage = [&](int jt, int bufi) {
        const int j0s = jt * 64;
        #pragma unroll
        for (int itr = 0; itr < 4; ++itr) {      // K: 64 rows x 16 chunks
            int chunk = itr * 256 + tid;
            int jj = chunk >> 4, pp = chunk & 15;
            int c = pp ^ (jj & 15) ^ ((jj >> 3) & 3);
            gload_lds16(kvp + ((size_t)(b * NN + j0s + jj)) * KVW + kvh * DD + c * 8,
                        &s_k[bufi][chunk * 8]);
        }
        #pragma unroll
        for (int itr = 0; itr < 4; ++itr) {      // V^T: 128 rows x 8 chunks
            int chunk = itr * 256 + tid;
            int d = chunk >> 3, pp = chunk & 7;
            int c = pp ^ (d & 7) ^ ((d >> 3) & 3);
            gload_lds16(vt + ((size_t)(b * KVHD + kvh) * DD + d) * NN + j0s + c * 8,
                        &s_v[bufi][chunk * 8]);
        }
    };

    stage(jlo, 0);
    for (int jt = jlo; jt < jhi; ++jt) {
        const int j0 = jt * 64;
        const int cur = (jt - jlo) & 1;
        __syncthreads();                           // buf[cur] ready
        if (jt + 1 < jhi) stage(jt + 1, cur ^ 1);  // prefetch during compute

        // S^T = K Q^T : two 32-j blocks; A=K-frag (row l5 / 32+l5), B=qf
        fx16 sc0 = {}, sc1 = {};
        #pragma unroll
        for (int kc = 0; kc < 8; ++kc) {
            int cs = ((kc * 2 + hi) ^ (l5 & 15) ^ ((l5 >> 3) & 3)) << 3;
            h8 k0 = *(const h8*)&s_k[cur][l5 * 128 + cs];
            h8 k1 = *(const h8*)&s_k[cur][(32 + l5) * 128 + cs];
            sc0 = mfma32h(k0, qf[kc], sc0);
            sc1 = mfma32h(k1, qf[kc], sc1);
        }

        const bool need_mask = (jt < 2 * x + 2);   // masked iters are in piece 0
        #pragma unroll
        for (int jb = 0; jb < 2; ++jb) {
            const fx16& sc = jb ? sc1 : sc0;
            // mask + exp + bf16 pack (verified byte order), in register order
            unsigned int pwod[8];
            #pragma unroll
            for (int pr = 0; pr < 8; ++pr) {
                float s0 = sc[2 * pr], s1 = sc[2 * pr + 1];
                if (need_mask) {
                    int rg0 = 2 * pr;              // even: rg0&3 in {0,2} -> jg1=jg0+1
                    int jg0 = j0 + jb * 32 + (rg0 & 3) + 8 * (rg0 >> 2) + 4 * hi;
                    if (jg0 <= qg) s0 = -1e9f;     // faithful inverted mask
                    if (jg0 + 1 <= qg) s1 = -1e9f;
                }
                pwod[pr] = (unsigned int)f2bf(__expf(s0)) |
                           ((unsigned int)f2bf(__expf(s1)) << 16);
            }
            u4v w0v = {pwod[0], pwod[1], pwod[2], pwod[3]};
            u4v w1v = {pwod[4], pwod[5], pwod[6], pwod[7]};
            b8 pa0 = __builtin_bit_cast(b8, w0v);  // k-slots 0..15  (regs 0..7)
            b8 pa1 = __builtin_bit_cast(b8, w1v);  // k-slots 16..31 (regs 8..15)

            // O += P V ; OS += P 1   (A[m=q=l5][k], B[n=d][k=j'])
            #pragma unroll
            for (int ks = 0; ks < 2; ++ks) {
                b8 pa = ks ? pa1 : pa0;
                #pragma unroll
                for (int dblk = 0; dblk < 4; ++dblk) {
                    b8 bv = *(const b8*)&s_v[cur][(dblk * 32 + l5) * 64 +
                             (((jb * 4 + ks * 2 + hi) ^ (l5 & 7) ^ ((l5 >> 3) & 3)) << 3)];
                    O[dblk] = mfma32b(pa, bv, O[dblk]);
                }
                OS = mfma32b(pa, ones, OS);
            }
        }
    }

    // epilogue. 32x32 C-layout: col=l5=d-local, row=(rg&3)+8*(rg>>2)+4*hi=q-local.
    if (is_split) {
        // write f32 partials (no divide) for combine_k
        size_t po = (((size_t)(b * NHD + h) * NSPLIT + x) * 2 + p);
        float* Op = O_ws + po * 16384;
        float* Lp = l_ws + po * 128;
        #pragma unroll
        for (int nt4 = 0; nt4 < 4; ++nt4)
            #pragma unroll
            for (int rg = 0; rg < 16; ++rg) {
                int q = (rg & 3) + 8 * (rg >> 2) + 4 * hi;
                Op[(w * 32 + q) * 128 + nt4 * 32 + l5] = O[nt4][rg];
            }
        if (l5 == 0) {
            #pragma unroll
            for (int rg = 0; rg < 16; ++rg) {
                int q = (rg & 3) + 8 * (rg >> 2) + 4 * hi;
                Lp[w * 32 + q] = OS[rg];
            }
        }
    } else {
        // Row N-1: l=0 -> NaN, overwritten by combine_k's fixup class.
        float inv_l[16];
        #pragma unroll
        for (int rg = 0; rg < 16; ++rg) inv_l[rg] = 1.0f / OS[rg];
        #pragma unroll
        for (int nt4 = 0; nt4 < 4; ++nt4)
            #pragma unroll
            for (int rg = 0; rg < 16; ++rg) {
                int q = (rg & 3) + 8 * (rg >> 2) + 4 * hi;
                ah[((size_t)(b * NN + i0 + w * 32 + q)) * HDIM + h * DD + nt4 * 32 + l5] =
                    (_Float16)(O[nt4][rg] * inv_l[rg]);
            }
    }
}

// ------- combine split partials: ah = (O0+O1)/(l0+l1); x==7 class = row N-1
// fixup (mean of V from vsum, which the fused QKV GEMM filled). grid (8,16,2).
__global__ __launch_bounds__(256) void combine_k(const float* __restrict__ O_ws,
                                                 const float* __restrict__ l_ws,
                                                 const float* __restrict__ vsum,
                                                 _Float16* __restrict__ ah) {
    const int x = blockIdx.x, h = blockIdx.y, b = blockIdx.z;
    const int tid = threadIdx.x;
    if (x == NSPLIT) {                       // row N-1 fixup for head h
        if (tid < 128) {
            float mean = vsum[((size_t)b * KVHD + (h & 3)) * DD + tid] * (1.0f / NN);
            ah[((size_t)(b * NN + NN - 1)) * HDIM + h * DD + tid] = (_Float16)mean;
        }
        return;
    }
    const int d = tid & 127;
    size_t po = (((size_t)(b * NHD + h) * NSPLIT + x) * 2);
    const float* O0 = O_ws + po * 16384;
    const float* O1 = O0 + 16384;
    const float* L0 = l_ws + po * 128;
    const float* L1 = L0 + 128;
    for (int ql = tid >> 7; ql < 128; ql += 2) {
        float l = L0[ql] + L1[ql];
        float o = O0[ql * 128 + d] + O1[ql * 128 + d];
        ah[((size_t)(b * NN + x * 128 + ql)) * HDIM + h * DD + d] = (_Float16)(o / l);
    }
}

extern "C" void kernel_launch(void* const* d_in, const int* in_sizes, int n_in,
                              void* d_out, int out_size, void* d_ws, size_t ws_size,
                              hipStream_t stream) {
    const float* tokens = (const float*)d_in[0];
    const float* norm_w = (const float*)d_in[1];
    const float* Wq = (const float*)d_in[2];
    const float* bq = (const float*)d_in[3];
    const float* Wk = (const float*)d_in[4];
    const float* bk = (const float*)d_in[5];
    const float* Wv = (const float*)d_in[6];
    const float* bv = (const float*)d_in[7];
    const float* Wo = (const float*)d_in[8];
    const float* bo = (const float*)d_in[9];
    float* out = (float*)d_out;

    char* ws = (char*)d_ws;
    _Float16* x_h   = (_Float16*)(ws);                        // 16 MB
    _Float16* wq_h  = (_Float16*)(ws + 16777216);             // 8 MB (contiguous with wkv)
    _Float16* wkv_h = (_Float16*)(ws + 25165824);             // 4 MB
    _Float16* wo_h  = (_Float16*)(ws + 29360128);             // 8 MB
    _Float16* q_h   = (_Float16*)(ws + 37752832);             // 16 MB
    _Float16* kv_h  = (_Float16*)(ws + 54530048);             // 8 MB (K region used)
    _Float16* a_h   = (_Float16*)(ws + 62918656);             // 16 MB
    unsigned short* vt_h = (unsigned short*)(ws + 79695872);  // 4 MB (bf16) -> ends 83890176
    float*    vsum  = (float*)   (ws + 83890176);             // 4 KB
    float*    l_ws  = (float*)   (ws + 83894272);             // 224 KB (448*128 f32)
    float*    bqkv  = (float*)   (ws + 84123648);             // 12 KB  -> ends 84135936
    // O_ws partials (448 pieces * 64 KB = 29,360,128 B) reuse the x_h/wq_h/wkv_h
    // region, which is dead after the merged QKV GEMM; ends exactly at wo_h.
    float*    O_ws  = (float*)(ws);

    // 5 launches total (was 10): launch-boundary gaps were ~1/4 of wall time.
    prep_k<<<MTOK + 10240 + 12, 256, 0, stream>>>(
        tokens, norm_w, Wq, Wk, Wv, Wo, bq, bk, bv,
        x_h, wq_h, wkv_h, wo_h, bqkv, vsum);

    // merged Q|K|V projection + fused V-transpose (vt) + fused vsum
    gemm_bt<2><<<dim3(3072 / 128, MTOK / 128), 256, 0, stream>>>(
        x_h, wq_h, bqkv, (void*)q_h, (void*)kv_h, vt_h, vsum, 3072, HDIM);

    attn_k<<<736, 256, 0, stream>>>(q_h, kv_h, vt_h, a_h, O_ws, l_ws);

    combine_k<<<dim3(NSPLIT + 1, NHD, BB), 256, 0, stream>>>(O_ws, l_ws, vsum, a_h);

    gemm_bt<1><<<dim3(HDIM / 128, MTOK / 128), 256, 0, stream>>>(
        a_h, wo_h, bo, (void*)out, nullptr, nullptr, nullptr, HDIM, HDIM);
}